// Round 11
// baseline (325.576 us; speedup 1.0000x reference)
//
#include <hip/hip_runtime.h>

// Problem constants (from reference)
#define KA 240000
#define NI 4
#define MG 50
#define NSEL 256u
#define CAPL 8192     // boundary-bin member cap per group (expect ~130)
#define MAGIC_F32 0x5EEDF32Au

typedef unsigned int u32;
typedef unsigned short u16;
typedef unsigned char u8;

// ws layout (u32 units):
//   hist  : [0, 16384)          8 groups x 2048 bins (key>>21)
//   meta  : [16384, 16424)      us11[8] | R[8] | done[8] | cnt[8] | pad
//   flagw : [16424]             dtype magic word (NOT zeroed; poison-safe protocol)
//   list  : [16432, 16432+8*CAPL*2)   (key, idx) boundary-bin members (512 KB)
//   keys  : u32[NI*KA]
//   flags : u8[NI*KA]
#define HISTN 16384
#define METAO HISTN
#define FLAGW 16424
#define LISTO 16432
#define KEYSO (LISTO + 8 * CAPL * 2)
#define FLAGO_BYTES ((KEYSO + NI * KA) * 4)

static __device__ __forceinline__ float bf2f(u16 h) {
    return __uint_as_float(((u32)h) << 16);
}
// monotone f32 -> u32 sortkey (order-preserving for all finite floats)
static __device__ __forceinline__ u32 sortkey32(float f) {
    u32 b = __float_as_uint(f);
    return (b & 0x80000000u) ? ~b : (b | 0x80000000u);
}

// ---------------- Init: zero hist+meta (parallel) + pipelined dtype sniff ----------------
// f32 anchors: first 32768 f32 words contain x coords up to ~1036 (>700 w.p. ~1).
// bf16-packed: word magnitude governed by high u16 = odd element (y coords < 691).
// On detection write MAGIC_F32 to ws[FLAGW]; any other value (0xAA poison) => bf16.
__global__ void kInit(const float* __restrict__ aF, u32* __restrict__ ws) {
    __shared__ u32 bflag;
    const int t = threadIdx.x;
    if (t == 0) bflag = 0;
    for (int i = blockIdx.x * 256 + t; i < FLAGW; i += gridDim.x * 256) ws[i] = 0;
    const int i0 = blockIdx.x * 512 + t;          // grid=64: covers 32768 words
    const float v0 = aF[i0];
    const float v1 = aF[i0 + 256];
    const bool hit = (v0 > 700.0f && v0 < 1.0e6f) || (v1 > 700.0f && v1 < 1.0e6f);
    __syncthreads();
    if (hit) bflag = 1;                            // benign LDS race (same value)
    __syncthreads();
    if (t == 0 && bflag) ws[FLAGW] = MAGIC_F32;    // all writers agree; no zeroing race
}

// ---------- main: exact-f32 IoU/argmax, 4 anchors/thread, fused LDS histogram ----------
extern "C" __global__ void AnchorTargetLayer_48052094107725_kernel(
    const void* __restrict__ anchorsV, const void* __restrict__ scoresV,
    const void* __restrict__ gtbV, const int* __restrict__ glab,
    float* __restrict__ out, u32* __restrict__ keys, u8* __restrict__ flags,
    u32* __restrict__ hist, const u32* __restrict__ wsflag) {
#pragma clang fp contract(off)
    __shared__ float4 gA[MG];
    __shared__ int glb[MG];
    __shared__ u32 lh[4096];          // [0,2048)=pos bins, [2048,4096)=neg bins
    const int n = blockIdx.y;
    const int tid = threadIdx.x;
    const bool isf32 = (wsflag[FLAGW] == MAGIC_F32);

    for (int i = tid; i < 4096; i += 256) lh[i] = 0;
    if (tid < MG) {
        float4 G;
        if (isf32) {
            G = ((const float4*)gtbV)[n * MG + tid];
        } else {
            const u32 w0 = ((const u32*)gtbV)[(n * MG + tid) * 2];
            const u32 w1 = ((const u32*)gtbV)[(n * MG + tid) * 2 + 1];
            G.x = __uint_as_float(w0 << 16);
            G.y = __uint_as_float(w0 & 0xFFFF0000u);
            G.z = __uint_as_float(w1 << 16);
            G.w = __uint_as_float(w1 & 0xFFFF0000u);
        }
        gA[tid] = G;
        glb[tid] = glab[n * MG + tid];
    }
    __syncthreads();

    const int k0 = (blockIdx.x * 256 + tid) * 4;   // 4 consecutive anchors (KA%4==0)
    if (k0 < KA) {
        float ax0[4], ay0[4], ax2[4], ay2[4];
        if (isf32) {
            #pragma unroll
            for (int j = 0; j < 4; ++j) {
                const float4 A = ((const float4*)anchorsV)[k0 + j];
                ax0[j] = A.x; ay0[j] = A.y; ax2[j] = A.z; ay2[j] = A.w;
            }
        } else {
            #pragma unroll
            for (int j = 0; j < 4; ++j) {
                const u32 w0 = ((const u32*)anchorsV)[2 * (k0 + j)];
                const u32 w1 = ((const u32*)anchorsV)[2 * (k0 + j) + 1];
                ax0[j] = __uint_as_float(w0 << 16);
                ay0[j] = __uint_as_float(w0 & 0xFFFF0000u);
                ax2[j] = __uint_as_float(w1 << 16);
                ay2[j] = __uint_as_float(w1 & 0xFFFF0000u);
            }
        }
        float aaw[4], aah[4], aar[4], bst[4];
        int bix[4];
        #pragma unroll
        for (int j = 0; j < 4; ++j) {
            aaw[j] = ax2[j] - ax0[j];
            aah[j] = ay2[j] - ay0[j];
            aar[j] = aaw[j] * aah[j];
            bst[j] = -1.0f;
            bix[j] = 0;
        }

        for (int m = 0; m < MG; m += 2) {
            const float4 Ga = gA[m];
            const float4 Gb = gA[m + 1];
            const float gaA = (Ga.z - Ga.x) * (Ga.w - Ga.y);  // same ops as reference
            const float gaB = (Gb.z - Gb.x) * (Gb.w - Gb.y);
            #pragma unroll
            for (int j = 0; j < 4; ++j) {
                const float wa = fmaxf(fminf(ax2[j], Ga.z) - fmaxf(ax0[j], Ga.x), 0.0f);
                const float ha = fmaxf(fminf(ay2[j], Ga.w) - fmaxf(ay0[j], Ga.y), 0.0f);
                const float ia = wa * ha;
                const float qa = ia / (((aar[j] + gaA) - ia) + 1e-8f);  // IEEE f32 div
                const float wb = fmaxf(fminf(ax2[j], Gb.z) - fmaxf(ax0[j], Gb.x), 0.0f);
                const float hb = fmaxf(fminf(ay2[j], Gb.w) - fmaxf(ay0[j], Gb.y), 0.0f);
                const float ib = wb * hb;
                const float qb = ib / (((aar[j] + gaB) - ib) + 1e-8f);
                if (qa > bst[j]) { bst[j] = qa; bix[j] = m; }      // strict >: first idx
                if (qb > bst[j]) { bst[j] = qb; bix[j] = m + 1; }
            }
        }

        // scores (vectorized)
        const int nk = n * KA + k0;
        float scv[4];
        if (isf32) {
            const float4 s4 = ((const float4*)scoresV)[nk >> 2];
            scv[0] = s4.x; scv[1] = s4.y; scv[2] = s4.z; scv[3] = s4.w;
        } else {
            const uint2 s2 = ((const uint2*)scoresV)[nk >> 2];
            scv[0] = bf2f((u16)(s2.x & 0xFFFFu));
            scv[1] = bf2f((u16)(s2.x >> 16));
            scv[2] = bf2f((u16)(s2.y & 0xFFFFu));
            scv[3] = bf2f((u16)(s2.y >> 16));
        }

        float clsv[4];
        float4 regv[4];
        u32 keyv[4];
        u32 flagpack = 0;
        #pragma unroll
        for (int j = 0; j < 4; ++j) {
            const bool pos = bst[j] >= 0.7f;
            const bool neg = bst[j] < 0.3f;
            clsv[j] = pos ? (float)glb[bix[j]] : 0.0f;
            float4 rv = make_float4(0.0f, 0.0f, 0.0f, 0.0f);
            if (pos) {
                const float4 Gm = gA[bix[j]];
                const float gw = Gm.z - Gm.x, gh = Gm.w - Gm.y;
                const float gcx = Gm.x + 0.5f * gw, gcy = Gm.y + 0.5f * gh;
                const float acx = ax0[j] + 0.5f * aaw[j], acy = ay0[j] + 0.5f * aah[j];
                rv.x = (gcx - acx) / aaw[j];
                rv.y = (gcy - acy) / aah[j];
                rv.z = logf(gw / aaw[j]);
                rv.w = logf(gh / aah[j]);
            }
            regv[j] = rv;
            keyv[j] = sortkey32(scv[j]);
            const u32 fl = pos ? 1u : (neg ? 2u : 0u);
            flagpack |= fl << (8 * j);
            if (fl) atomicAdd(&lh[(fl == 2u ? 2048 : 0) + (keyv[j] >> 21)], 1u);
        }

        // vectorized stores
        const size_t NK = (size_t)NI * KA;
        ((float4*)out)[nk >> 2] = make_float4(clsv[0], clsv[1], clsv[2], clsv[3]);
        float4* regp = ((float4*)(out + NK)) + nk;
        regp[0] = regv[0]; regp[1] = regv[1]; regp[2] = regv[2]; regp[3] = regv[3];
        ((uint4*)keys)[nk >> 2] = make_uint4(keyv[0], keyv[1], keyv[2], keyv[3]);
        ((u32*)flags)[nk >> 2] = flagpack;
    }

    __syncthreads();
    // merge block-local histogram (16 KB global region -> negligible write amp)
    const int hb = (2 * n) * 2048;
    for (int i = tid; i < 4096; i += 256) {
        const u32 c = lh[i];
        if (c) atomicAdd(&hist[hb + i], c);
    }
}

// ---------------- B: per-group boundary 11-bit bin (8 blocks, 2048-bin scan) ----------------
__global__ void kB(const u32* __restrict__ hist, u32* __restrict__ meta) {
    __shared__ u32 cs[256];
    const int g = blockIdx.x, t = threadIdx.x;
    u32 loc[8];
    u32 s = 0;
    const int base = g * 2048 + t * 8;
    #pragma unroll
    for (int j = 0; j < 8; ++j) { loc[j] = hist[base + j]; s += loc[j]; }
    cs[t] = s;
    __syncthreads();
    for (int d = 1; d < 256; d <<= 1) {
        const u32 add = (t + d < 256) ? cs[t + d] : 0u;
        __syncthreads();
        cs[t] += add;
        __syncthreads();
    }
    if (t == 0) meta[16 + g] = (cs[0] < NSEL) ? 1u : 0u;  // done: <256 members, take all
    u32 run = (t < 255) ? cs[t + 1] : 0u;   // suffix sum of chunks after mine
    for (int j = 7; j >= 0; --j) {          // bins high -> low within chunk
        const u32 Sj = run + loc[j];
        if (Sj >= NSEL && run < NSEL) {
            meta[g] = (u32)(t * 8 + j);     // us11: boundary 11-bit prefix
            meta[8 + g] = NSEL - run;       // R: slots within boundary bin
        }
        run = Sj;
    }
}

// ---------------- T: collect boundary-bin members (~130/group) ----------------
__global__ void kT(const u32* __restrict__ keys, const u8* __restrict__ flags,
                   u32* __restrict__ meta, u32* __restrict__ list) {
    const int idx = blockIdx.x * 256 + threadIdx.x;
    if (idx >= NI * KA) return;
    const u8 f = flags[idx];
    if (!f) return;
    const int n = idx / KA;
    const int g = 2 * n + (f == 2 ? 1 : 0);
    if (meta[16 + g]) return;
    const u32 key = keys[idx];
    if ((key >> 21) == meta[g]) {
        const u32 p = atomicAdd(&meta[24 + g], 1u);
        if (p < CAPL) {
            list[(g * CAPL + p) * 2] = key;
            list[(g * CAPL + p) * 2 + 1] = (u32)(idx - n * KA);
        }
    }
}

// ---------------- F: final mask -> cls_weights / reg_weights ----------------
__global__ void kF(const u32* __restrict__ keys, const u8* __restrict__ flags,
                   const u32* __restrict__ meta, const u32* __restrict__ list,
                   float* __restrict__ out) {
    const int k = blockIdx.x * 256 + threadIdx.x;
    if (k >= KA) return;
    const int n = blockIdx.y;
    const int idx = n * KA + k;
    const u8 f = flags[idx];
    bool in = false;
    if (f) {
        const int g = 2 * n + (f == 2 ? 1 : 0);
        if (meta[16 + g]) {
            in = true;                        // group < 256 members: take all
        } else {
            const u32 key = keys[idx];
            const u32 us = meta[g];
            const u32 p11 = key >> 21;
            if (p11 > us) in = true;
            else if (p11 == us) {
                // stable rank among boundary-bin members: (key desc, idx asc)
                u32 c = meta[24 + g];
                if (c > CAPL) c = CAPL;
                const u32 R = meta[8 + g];
                u32 rank = 0;
                for (u32 j = 0; j < c; ++j) {
                    const u32 kj = list[(g * CAPL + j) * 2];
                    const u32 ij = list[(g * CAPL + j) * 2 + 1];
                    if (kj > key || (kj == key && ij < (u32)k)) rank++;
                }
                in = (rank < R);
            }
        }
    }
    const size_t NK = (size_t)NI * KA;
    out[5 * NK + idx] = in ? 1.0f : 0.0f;              // cls_weights
    out[6 * NK + idx] = (in && f == 1) ? 1.0f : 0.0f;  // reg_weights
}

extern "C" void kernel_launch(void* const* d_in, const int* in_sizes, int n_in,
                              void* d_out, int out_size, void* d_ws, size_t ws_size,
                              hipStream_t stream) {
    (void)in_sizes; (void)n_in; (void)out_size; (void)ws_size;
    const void* anchors = d_in[0];   // (K,4)  f32 (bf16 fallback sniffed)
    const void* scores  = d_in[1];   // (N,K)
    const void* gtb     = d_in[2];   // (N,M,4)
    const int*  glab    = (const int*)d_in[3];   // (N,M) int32
    float* out = (float*)d_out;

    u32* ws   = (u32*)d_ws;
    u32* hist = ws;
    u32* meta = ws + METAO;
    u32* list = ws + LISTO;
    u32* keys = ws + KEYSO;
    u8*  flags = (u8*)((char*)d_ws + FLAGO_BYTES);

    const int GB4 = (KA / 4 + 255) / 256;   // 235
    const int GB  = (KA + 255) / 256;       // 938
    kInit<<<64, 256, 0, stream>>>((const float*)anchors, ws);
    AnchorTargetLayer_48052094107725_kernel<<<dim3(GB4, NI), 256, 0, stream>>>(
        anchors, scores, gtb, glab, out, keys, flags, hist, ws);
    kB<<<8, 256, 0, stream>>>(hist, meta);
    kT<<<(NI * KA + 255) / 256, 256, 0, stream>>>(keys, flags, meta, list);
    kF<<<dim3(GB, NI), 256, 0, stream>>>(keys, flags, meta, list, out);
}

// Round 12
// 268.910 us; speedup vs baseline: 1.2107x; 1.2107x over previous
//
#include <hip/hip_runtime.h>

// Problem constants (from reference)
#define KA 240000
#define NI 4
#define MG 50
#define NSEL 256u
#define CAPL 4096     // boundary-bin member cap per group (expect ~260)
#define MAGIC_F32 0x5EEDF32Au

typedef unsigned int u32;
typedef unsigned short u16;
typedef unsigned char u8;

// ws layout (u32 units):
//   hist  : [0, 16384)          8 groups x 2048 bins (key>>21)
//   meta  : [16384, 16424)      us11[8] | R[8] | done[8] | cnt[8] | pad
//   flagw : [16424]             dtype magic word (NOT zeroed; poison-safe protocol)
//   list  : [16432, 16432+8*CAPL*2)   (key, idx) boundary-bin members (256 KB)
//   keys  : u32[NI*KA]
//   flags : u8[NI*KA]
#define HISTN 16384
#define METAO HISTN
#define FLAGW 16424
#define LISTO 16432
#define KEYSO (LISTO + 8 * CAPL * 2)
#define FLAGO_BYTES ((KEYSO + NI * KA) * 4)

static __device__ __forceinline__ float bf2f(u16 h) {
    return __uint_as_float(((u32)h) << 16);
}
// monotone f32 -> u32 sortkey (order-preserving for all finite floats)
static __device__ __forceinline__ u32 sortkey32(float f) {
    u32 b = __float_as_uint(f);
    return (b & 0x80000000u) ? ~b : (b | 0x80000000u);
}

// ---------------- Init: zero hist+meta (parallel) + dtype sniff ----------------
__global__ void kInit(const float* __restrict__ aF, u32* __restrict__ ws) {
    __shared__ u32 bflag;
    const int t = threadIdx.x;
    if (t == 0) bflag = 0;
    for (int i = blockIdx.x * 256 + t; i < FLAGW; i += gridDim.x * 256) ws[i] = 0;
    const int i0 = blockIdx.x * 512 + t;          // grid=64: covers 32768 words
    const float v0 = aF[i0];
    const float v1 = aF[i0 + 256];
    const bool hit = (v0 > 700.0f && v0 < 1.0e6f) || (v1 > 700.0f && v1 < 1.0e6f);
    __syncthreads();
    if (hit) bflag = 1;                            // benign LDS race (same value)
    __syncthreads();
    if (t == 0 && bflag) ws[FLAGW] = MAGIC_F32;    // f32 anchors have x coords > 700
}

// ---------- main: exact-f32 IoU/argmax, 4 anchors/thread, fused LDS histogram ----------
extern "C" __global__ void AnchorTargetLayer_48052094107725_kernel(
    const void* __restrict__ anchorsV, const void* __restrict__ scoresV,
    const void* __restrict__ gtbV, const int* __restrict__ glab,
    float* __restrict__ out, u32* __restrict__ keys, u8* __restrict__ flags,
    u32* __restrict__ hist, const u32* __restrict__ wsflag) {
#pragma clang fp contract(off)
    __shared__ float4 gA[MG];
    __shared__ int glb[MG];
    __shared__ u32 lh[4096];          // [0,2048)=pos bins, [2048,4096)=neg bins
    const int n = blockIdx.y;
    const int tid = threadIdx.x;
    const bool isf32 = (wsflag[FLAGW] == MAGIC_F32);

    for (int i = tid; i < 4096; i += 256) lh[i] = 0;
    if (tid < MG) {
        float4 G;
        if (isf32) {
            G = ((const float4*)gtbV)[n * MG + tid];
        } else {
            const u32 w0 = ((const u32*)gtbV)[(n * MG + tid) * 2];
            const u32 w1 = ((const u32*)gtbV)[(n * MG + tid) * 2 + 1];
            G.x = __uint_as_float(w0 << 16);
            G.y = __uint_as_float(w0 & 0xFFFF0000u);
            G.z = __uint_as_float(w1 << 16);
            G.w = __uint_as_float(w1 & 0xFFFF0000u);
        }
        gA[tid] = G;
        glb[tid] = glab[n * MG + tid];
    }
    __syncthreads();

    const int k0 = (blockIdx.x * 256 + tid) * 4;   // 4 consecutive anchors (KA%4==0)
    if (k0 < KA) {
        float ax0[4], ay0[4], ax2[4], ay2[4];
        if (isf32) {
            #pragma unroll
            for (int j = 0; j < 4; ++j) {
                const float4 A = ((const float4*)anchorsV)[k0 + j];
                ax0[j] = A.x; ay0[j] = A.y; ax2[j] = A.z; ay2[j] = A.w;
            }
        } else {
            #pragma unroll
            for (int j = 0; j < 4; ++j) {
                const u32 w0 = ((const u32*)anchorsV)[2 * (k0 + j)];
                const u32 w1 = ((const u32*)anchorsV)[2 * (k0 + j) + 1];
                ax0[j] = __uint_as_float(w0 << 16);
                ay0[j] = __uint_as_float(w0 & 0xFFFF0000u);
                ax2[j] = __uint_as_float(w1 << 16);
                ay2[j] = __uint_as_float(w1 & 0xFFFF0000u);
            }
        }
        float aaw[4], aah[4], aar[4], bst[4];
        int bix[4];
        #pragma unroll
        for (int j = 0; j < 4; ++j) {
            aaw[j] = ax2[j] - ax0[j];
            aah[j] = ay2[j] - ay0[j];
            aar[j] = aaw[j] * aah[j];
            bst[j] = -1.0f;
            bix[j] = 0;
        }

        for (int m = 0; m < MG; m += 2) {
            const float4 Ga = gA[m];
            const float4 Gb = gA[m + 1];
            const float gaA = (Ga.z - Ga.x) * (Ga.w - Ga.y);  // same ops as reference
            const float gaB = (Gb.z - Gb.x) * (Gb.w - Gb.y);
            #pragma unroll
            for (int j = 0; j < 4; ++j) {
                const float wa = fmaxf(fminf(ax2[j], Ga.z) - fmaxf(ax0[j], Ga.x), 0.0f);
                const float ha = fmaxf(fminf(ay2[j], Ga.w) - fmaxf(ay0[j], Ga.y), 0.0f);
                const float ia = wa * ha;
                const float qa = ia / (((aar[j] + gaA) - ia) + 1e-8f);  // IEEE f32 div
                const float wb = fmaxf(fminf(ax2[j], Gb.z) - fmaxf(ax0[j], Gb.x), 0.0f);
                const float hb = fmaxf(fminf(ay2[j], Gb.w) - fmaxf(ay0[j], Gb.y), 0.0f);
                const float ib = wb * hb;
                const float qb = ib / (((aar[j] + gaB) - ib) + 1e-8f);
                if (qa > bst[j]) { bst[j] = qa; bix[j] = m; }      // strict >: first idx
                if (qb > bst[j]) { bst[j] = qb; bix[j] = m + 1; }
            }
        }

        const int nk = n * KA + k0;
        float scv[4];
        if (isf32) {
            const float4 s4 = ((const float4*)scoresV)[nk >> 2];
            scv[0] = s4.x; scv[1] = s4.y; scv[2] = s4.z; scv[3] = s4.w;
        } else {
            const uint2 s2 = ((const uint2*)scoresV)[nk >> 2];
            scv[0] = bf2f((u16)(s2.x & 0xFFFFu));
            scv[1] = bf2f((u16)(s2.x >> 16));
            scv[2] = bf2f((u16)(s2.y & 0xFFFFu));
            scv[3] = bf2f((u16)(s2.y >> 16));
        }

        float clsv[4];
        float4 regv[4];
        u32 keyv[4];
        u32 flagpack = 0;
        #pragma unroll
        for (int j = 0; j < 4; ++j) {
            const bool pos = bst[j] >= 0.7f;
            const bool neg = bst[j] < 0.3f;
            clsv[j] = pos ? (float)glb[bix[j]] : 0.0f;
            float4 rv = make_float4(0.0f, 0.0f, 0.0f, 0.0f);
            if (pos) {
                const float4 Gm = gA[bix[j]];
                const float gw = Gm.z - Gm.x, gh = Gm.w - Gm.y;
                const float gcx = Gm.x + 0.5f * gw, gcy = Gm.y + 0.5f * gh;
                const float acx = ax0[j] + 0.5f * aaw[j], acy = ay0[j] + 0.5f * aah[j];
                rv.x = (gcx - acx) / aaw[j];
                rv.y = (gcy - acy) / aah[j];
                rv.z = logf(gw / aaw[j]);
                rv.w = logf(gh / aah[j]);
            }
            regv[j] = rv;
            keyv[j] = sortkey32(scv[j]);
            const u32 fl = pos ? 1u : (neg ? 2u : 0u);
            flagpack |= fl << (8 * j);
            if (fl) atomicAdd(&lh[(fl == 2u ? 2048 : 0) + (keyv[j] >> 21)], 1u);
        }

        const size_t NK = (size_t)NI * KA;
        ((float4*)out)[nk >> 2] = make_float4(clsv[0], clsv[1], clsv[2], clsv[3]);
        float4* regp = ((float4*)(out + NK)) + nk;
        regp[0] = regv[0]; regp[1] = regv[1]; regp[2] = regv[2]; regp[3] = regv[3];
        ((uint4*)keys)[nk >> 2] = make_uint4(keyv[0], keyv[1], keyv[2], keyv[3]);
        ((u32*)flags)[nk >> 2] = flagpack;
    }

    __syncthreads();
    const int hb = (2 * n) * 2048;
    for (int i = tid; i < 4096; i += 256) {
        const u32 c = lh[i];
        if (c) atomicAdd(&hist[hb + i], c);
    }
}

// ---------------- B: per-group boundary 11-bit bin (8 blocks) ----------------
__global__ void kB(const u32* __restrict__ hist, u32* __restrict__ meta) {
    __shared__ u32 cs[256];
    const int g = blockIdx.x, t = threadIdx.x;
    u32 loc[8];
    u32 s = 0;
    const int base = g * 2048 + t * 8;
    #pragma unroll
    for (int j = 0; j < 8; ++j) { loc[j] = hist[base + j]; s += loc[j]; }
    cs[t] = s;
    __syncthreads();
    for (int d = 1; d < 256; d <<= 1) {
        const u32 add = (t + d < 256) ? cs[t + d] : 0u;
        __syncthreads();
        cs[t] += add;
        __syncthreads();
    }
    if (t == 0) meta[16 + g] = (cs[0] < NSEL) ? 1u : 0u;  // done: <256 members, take all
    u32 run = (t < 255) ? cs[t + 1] : 0u;   // suffix sum of chunks after mine
    for (int j = 7; j >= 0; --j) {          // bins high -> low within chunk
        const u32 Sj = run + loc[j];
        if (Sj >= NSEL && run < NSEL) {
            meta[g] = (u32)(t * 8 + j);     // us11: boundary 11-bit prefix
            meta[8 + g] = NSEL - run;       // R: slots within boundary bin
        }
        run = Sj;
    }
}

// ------- FT: fused streaming pass — weights for decided anchors + tie collection -------
__global__ void kFT(const u32* __restrict__ keys, const u8* __restrict__ flags,
                    u32* __restrict__ meta, u32* __restrict__ list,
                    float* __restrict__ out) {
    const int idx = blockIdx.x * 256 + threadIdx.x;
    if (idx >= NI * KA) return;
    const u8 f = flags[idx];
    bool in = false;
    if (f) {
        const int n = idx / KA;
        const int g = 2 * n + (f == 2 ? 1 : 0);
        if (meta[16 + g]) {
            in = true;                        // group < 256 members: take all
        } else {
            const u32 key = keys[idx];
            const u32 us = meta[g];
            const u32 p11 = key >> 21;
            if (p11 > us) {
                in = true;
            } else if (p11 == us) {
                // boundary-bin member: defer verdict to kR (write 0 now)
                const u32 p = atomicAdd(&meta[24 + g], 1u);
                if (p < CAPL) {
                    list[(g * CAPL + p) * 2] = key;
                    list[(g * CAPL + p) * 2 + 1] = (u32)(idx - n * KA);
                }
            }
        }
    }
    const size_t NK = (size_t)NI * KA;
    out[5 * NK + idx] = in ? 1.0f : 0.0f;              // cls_weights
    out[6 * NK + idx] = (in && f == 1) ? 1.0f : 0.0f;  // reg_weights
}

// ------- R: rank boundary-bin members in LDS, fix up selected ones (8 blocks) -------
__global__ void kR(const u32* __restrict__ meta, const u32* __restrict__ list,
                   float* __restrict__ out) {
    __shared__ u32 lk[CAPL];
    __shared__ u32 li[CAPL];
    const int g = blockIdx.x;
    const int t = threadIdx.x;
    if (meta[16 + g]) return;                 // take-all group already handled
    u32 c = meta[24 + g];
    if (c > CAPL) c = CAPL;
    const u32 R = meta[8 + g];
    for (u32 j = t; j < c; j += 256) {
        lk[j] = list[(g * CAPL + j) * 2];
        li[j] = list[(g * CAPL + j) * 2 + 1];
    }
    __syncthreads();
    const int n = g >> 1;
    const bool posg = ((g & 1) == 0);
    const size_t NK = (size_t)NI * KA;
    for (u32 i = t; i < c; i += 256) {
        const u32 ki = lk[i], ii = li[i];
        u32 rank = 0;
        for (u32 j = 0; j < c; ++j) {         // LDS broadcast reads: conflict-free
            const u32 kj = lk[j];
            if (kj > ki || (kj == ki && li[j] < ii)) rank++;
        }
        if (rank < R) {                       // stable top_k: (key desc, idx asc)
            const int oidx = n * KA + (int)ii;
            out[5 * NK + oidx] = 1.0f;
            if (posg) out[6 * NK + oidx] = 1.0f;
        }
    }
}

extern "C" void kernel_launch(void* const* d_in, const int* in_sizes, int n_in,
                              void* d_out, int out_size, void* d_ws, size_t ws_size,
                              hipStream_t stream) {
    (void)in_sizes; (void)n_in; (void)out_size; (void)ws_size;
    const void* anchors = d_in[0];   // (K,4)  f32 (bf16 fallback sniffed)
    const void* scores  = d_in[1];   // (N,K)
    const void* gtb     = d_in[2];   // (N,M,4)
    const int*  glab    = (const int*)d_in[3];   // (N,M) int32
    float* out = (float*)d_out;

    u32* ws   = (u32*)d_ws;
    u32* hist = ws;
    u32* meta = ws + METAO;
    u32* list = ws + LISTO;
    u32* keys = ws + KEYSO;
    u8*  flags = (u8*)((char*)d_ws + FLAGO_BYTES);

    const int GB4 = (KA / 4 + 255) / 256;   // 235
    kInit<<<64, 256, 0, stream>>>((const float*)anchors, ws);
    AnchorTargetLayer_48052094107725_kernel<<<dim3(GB4, NI), 256, 0, stream>>>(
        anchors, scores, gtb, glab, out, keys, flags, hist, ws);
    kB<<<8, 256, 0, stream>>>(hist, meta);
    kFT<<<(NI * KA + 255) / 256, 256, 0, stream>>>(keys, flags, meta, list, out);
    kR<<<8, 256, 0, stream>>>(meta, list, out);
}

// Round 13
// 139.539 us; speedup vs baseline: 2.3332x; 1.9271x over previous
//
#include <hip/hip_runtime.h>

// Problem constants (from reference)
#define KA 240000
#define NI 4
#define MG 50
#define NSEL 256u
#define CAPL 4096     // boundary-bin member cap per group (expect ~260)
#define MAGIC_F32 0x5EEDF32Au

typedef unsigned int u32;
typedef unsigned short u16;
typedef unsigned char u8;

// ws layout (u32 units):
//   hist  : [0, 16384)          8 groups x 2048 bins (key>>21)
//   meta  : [16384, 16424)      us11[8] | R[8] | done[8] | cnt[8] | pad
//   flagw : [16424]             dtype magic word (NOT zeroed; poison-safe protocol)
//   list  : [16432, 16432+8*CAPL*2)   (key, idx) boundary-bin members (256 KB)
//   keys  : u32[NI*KA]
//   flags : u8[NI*KA]
#define HISTN 16384
#define METAO HISTN
#define FLAGW 16424
#define LISTO 16432
#define KEYSO (LISTO + 8 * CAPL * 2)
#define FLAGO_BYTES ((KEYSO + NI * KA) * 4)

static __device__ __forceinline__ float bf2f(u16 h) {
    return __uint_as_float(((u32)h) << 16);
}
// monotone f32 -> u32 sortkey (order-preserving for all finite floats)
static __device__ __forceinline__ u32 sortkey32(float f) {
    u32 b = __float_as_uint(f);
    return (b & 0x80000000u) ? ~b : (b | 0x80000000u);
}

// ---------------- Init: zero hist+meta (parallel) + dtype sniff ----------------
__global__ void kInit(const float* __restrict__ aF, u32* __restrict__ ws) {
    __shared__ u32 bflag;
    const int t = threadIdx.x;
    if (t == 0) bflag = 0;
    for (int i = blockIdx.x * 256 + t; i < FLAGW; i += gridDim.x * 256) ws[i] = 0;
    const int i0 = blockIdx.x * 512 + t;          // grid=64: covers 32768 words
    const float v0 = aF[i0];
    const float v1 = aF[i0 + 256];
    const bool hit = (v0 > 700.0f && v0 < 1.0e6f) || (v1 > 700.0f && v1 < 1.0e6f);
    __syncthreads();
    if (hit) bflag = 1;                            // benign LDS race (same value)
    __syncthreads();
    if (t == 0 && bflag) ws[FLAGW] = MAGIC_F32;    // f32 anchors have x coords > 700
}

// ---------- main: exact-f32 IoU/argmax, 4 anchors/thread, fused LDS histogram ----------
extern "C" __global__ void AnchorTargetLayer_48052094107725_kernel(
    const void* __restrict__ anchorsV, const void* __restrict__ scoresV,
    const void* __restrict__ gtbV, const int* __restrict__ glab,
    float* __restrict__ out, u32* __restrict__ keys, u8* __restrict__ flags,
    u32* __restrict__ hist, const u32* __restrict__ wsflag) {
#pragma clang fp contract(off)
    __shared__ float4 gA[MG];
    __shared__ int glb[MG];
    __shared__ u32 lh[4096];          // [0,2048)=pos bins, [2048,4096)=neg bins
    const int n = blockIdx.y;
    const int tid = threadIdx.x;
    const bool isf32 = (wsflag[FLAGW] == MAGIC_F32);

    for (int i = tid; i < 4096; i += 256) lh[i] = 0;
    if (tid < MG) {
        float4 G;
        if (isf32) {
            G = ((const float4*)gtbV)[n * MG + tid];
        } else {
            const u32 w0 = ((const u32*)gtbV)[(n * MG + tid) * 2];
            const u32 w1 = ((const u32*)gtbV)[(n * MG + tid) * 2 + 1];
            G.x = __uint_as_float(w0 << 16);
            G.y = __uint_as_float(w0 & 0xFFFF0000u);
            G.z = __uint_as_float(w1 << 16);
            G.w = __uint_as_float(w1 & 0xFFFF0000u);
        }
        gA[tid] = G;
        glb[tid] = glab[n * MG + tid];
    }
    __syncthreads();

    const int k0 = (blockIdx.x * 256 + tid) * 4;   // 4 consecutive anchors (KA%4==0)
    if (k0 < KA) {
        float ax0[4], ay0[4], ax2[4], ay2[4];
        if (isf32) {
            #pragma unroll
            for (int j = 0; j < 4; ++j) {
                const float4 A = ((const float4*)anchorsV)[k0 + j];
                ax0[j] = A.x; ay0[j] = A.y; ax2[j] = A.z; ay2[j] = A.w;
            }
        } else {
            #pragma unroll
            for (int j = 0; j < 4; ++j) {
                const u32 w0 = ((const u32*)anchorsV)[2 * (k0 + j)];
                const u32 w1 = ((const u32*)anchorsV)[2 * (k0 + j) + 1];
                ax0[j] = __uint_as_float(w0 << 16);
                ay0[j] = __uint_as_float(w0 & 0xFFFF0000u);
                ax2[j] = __uint_as_float(w1 << 16);
                ay2[j] = __uint_as_float(w1 & 0xFFFF0000u);
            }
        }
        float aaw[4], aah[4], aar[4], bst[4];
        int bix[4];
        #pragma unroll
        for (int j = 0; j < 4; ++j) {
            aaw[j] = ax2[j] - ax0[j];
            aah[j] = ay2[j] - ay0[j];
            aar[j] = aaw[j] * aah[j];
            bst[j] = -1.0f;
            bix[j] = 0;
        }

        for (int m = 0; m < MG; m += 2) {
            const float4 Ga = gA[m];
            const float4 Gb = gA[m + 1];
            const float gaA = (Ga.z - Ga.x) * (Ga.w - Ga.y);  // same ops as reference
            const float gaB = (Gb.z - Gb.x) * (Gb.w - Gb.y);
            #pragma unroll
            for (int j = 0; j < 4; ++j) {
                const float wa = fmaxf(fminf(ax2[j], Ga.z) - fmaxf(ax0[j], Ga.x), 0.0f);
                const float ha = fmaxf(fminf(ay2[j], Ga.w) - fmaxf(ay0[j], Ga.y), 0.0f);
                const float ia = wa * ha;
                const float qa = ia / (((aar[j] + gaA) - ia) + 1e-8f);  // IEEE f32 div
                const float wb = fmaxf(fminf(ax2[j], Gb.z) - fmaxf(ax0[j], Gb.x), 0.0f);
                const float hb = fmaxf(fminf(ay2[j], Gb.w) - fmaxf(ay0[j], Gb.y), 0.0f);
                const float ib = wb * hb;
                const float qb = ib / (((aar[j] + gaB) - ib) + 1e-8f);
                if (qa > bst[j]) { bst[j] = qa; bix[j] = m; }      // strict >: first idx
                if (qb > bst[j]) { bst[j] = qb; bix[j] = m + 1; }
            }
        }

        const int nk = n * KA + k0;
        float scv[4];
        if (isf32) {
            const float4 s4 = ((const float4*)scoresV)[nk >> 2];
            scv[0] = s4.x; scv[1] = s4.y; scv[2] = s4.z; scv[3] = s4.w;
        } else {
            const uint2 s2 = ((const uint2*)scoresV)[nk >> 2];
            scv[0] = bf2f((u16)(s2.x & 0xFFFFu));
            scv[1] = bf2f((u16)(s2.x >> 16));
            scv[2] = bf2f((u16)(s2.y & 0xFFFFu));
            scv[3] = bf2f((u16)(s2.y >> 16));
        }

        float clsv[4];
        float4 regv[4];
        u32 keyv[4];
        u32 flagpack = 0;
        #pragma unroll
        for (int j = 0; j < 4; ++j) {
            const bool pos = bst[j] >= 0.7f;
            const bool neg = bst[j] < 0.3f;
            clsv[j] = pos ? (float)glb[bix[j]] : 0.0f;
            float4 rv = make_float4(0.0f, 0.0f, 0.0f, 0.0f);
            if (pos) {
                const float4 Gm = gA[bix[j]];
                const float gw = Gm.z - Gm.x, gh = Gm.w - Gm.y;
                const float gcx = Gm.x + 0.5f * gw, gcy = Gm.y + 0.5f * gh;
                const float acx = ax0[j] + 0.5f * aaw[j], acy = ay0[j] + 0.5f * aah[j];
                rv.x = (gcx - acx) / aaw[j];
                rv.y = (gcy - acy) / aah[j];
                rv.z = logf(gw / aaw[j]);
                rv.w = logf(gh / aah[j]);
            }
            regv[j] = rv;
            keyv[j] = sortkey32(scv[j]);
            const u32 fl = pos ? 1u : (neg ? 2u : 0u);
            flagpack |= fl << (8 * j);
            if (fl) atomicAdd(&lh[(fl == 2u ? 2048 : 0) + (keyv[j] >> 21)], 1u);
        }

        const size_t NK = (size_t)NI * KA;
        ((float4*)out)[nk >> 2] = make_float4(clsv[0], clsv[1], clsv[2], clsv[3]);
        float4* regp = ((float4*)(out + NK)) + nk;
        regp[0] = regv[0]; regp[1] = regv[1]; regp[2] = regv[2]; regp[3] = regv[3];
        ((uint4*)keys)[nk >> 2] = make_uint4(keyv[0], keyv[1], keyv[2], keyv[3]);
        ((u32*)flags)[nk >> 2] = flagpack;
    }

    __syncthreads();
    const int hb = (2 * n) * 2048;
    for (int i = tid; i < 4096; i += 256) {
        const u32 c = lh[i];
        if (c) atomicAdd(&hist[hb + i], c);
    }
}

// ---------------- B: per-group boundary 11-bit bin (8 blocks) ----------------
__global__ void kB(const u32* __restrict__ hist, u32* __restrict__ meta) {
    __shared__ u32 cs[256];
    const int g = blockIdx.x, t = threadIdx.x;
    u32 loc[8];
    u32 s = 0;
    const int base = g * 2048 + t * 8;
    #pragma unroll
    for (int j = 0; j < 8; ++j) { loc[j] = hist[base + j]; s += loc[j]; }
    cs[t] = s;
    __syncthreads();
    for (int d = 1; d < 256; d <<= 1) {
        const u32 add = (t + d < 256) ? cs[t + d] : 0u;
        __syncthreads();
        cs[t] += add;
        __syncthreads();
    }
    if (t == 0) meta[16 + g] = (cs[0] < NSEL) ? 1u : 0u;  // done: <256 members, take all
    u32 run = (t < 255) ? cs[t + 1] : 0u;   // suffix sum of chunks after mine
    for (int j = 7; j >= 0; --j) {          // bins high -> low within chunk
        const u32 Sj = run + loc[j];
        if (Sj >= NSEL && run < NSEL) {
            meta[g] = (u32)(t * 8 + j);     // us11: boundary 11-bit prefix
            meta[8 + g] = NSEL - run;       // R1: slots within boundary bin
        }
        run = Sj;
    }
}

// ------- FT: streaming weights (4 anchors/thread, float4 stores) + tie collection -------
__global__ void kFT(const u32* __restrict__ keys, const u32* __restrict__ flagsW,
                    u32* __restrict__ meta, u32* __restrict__ list,
                    float* __restrict__ out) {
    const int t4 = blockIdx.x * 256 + threadIdx.x;   // one thread per 4 anchors
    if (t4 >= (NI * KA) / 4) return;
    const int idx0 = t4 * 4;
    const int n = idx0 / KA;                          // same n for all 4 (KA%4==0)
    const int k0 = idx0 - n * KA;
    const u32 fw = flagsW[t4];
    const uint4 kv = ((const uint4*)keys)[t4];
    const u32 gp = 2 * n, gn = 2 * n + 1;
    const u32 doneP = meta[16 + gp], doneN = meta[16 + gn];
    const u32 usP = meta[gp], usN = meta[gn];

    float cw[4], rw[4];
    const u32 kk[4] = {kv.x, kv.y, kv.z, kv.w};
    #pragma unroll
    for (int j = 0; j < 4; ++j) {
        const u32 f = (fw >> (8 * j)) & 255u;
        bool in = false;
        if (f) {
            const u32 g = (f == 2u) ? gn : gp;
            const u32 done = (f == 2u) ? doneN : doneP;
            const u32 us = (f == 2u) ? usN : usP;
            if (done) {
                in = true;                     // group < 256 members: take all
            } else {
                const u32 p11 = kk[j] >> 21;
                if (p11 > us) {
                    in = true;
                } else if (p11 == us) {
                    // boundary-bin member: defer verdict to kR2 (weight stays 0)
                    const u32 p = atomicAdd(&meta[24 + g], 1u);
                    if (p < CAPL) {
                        list[(g * CAPL + p) * 2] = kk[j];
                        list[(g * CAPL + p) * 2 + 1] = (u32)(k0 + j);
                    }
                }
            }
        }
        cw[j] = in ? 1.0f : 0.0f;
        rw[j] = (in && f == 1u) ? 1.0f : 0.0f;
    }
    const size_t NK4 = (size_t)(NI * KA) / 4;
    ((float4*)out)[5 * NK4 + t4] = make_float4(cw[0], cw[1], cw[2], cw[3]);
    ((float4*)out)[6 * NK4 + t4] = make_float4(rw[0], rw[1], rw[2], rw[3]);
}

// ------- R2: block-local 21-bit refinement + tiny tie ranking (8 blocks) -------
__global__ void kR2(const u32* __restrict__ meta, const u32* __restrict__ list,
                    float* __restrict__ out) {
    __shared__ u32 lk[CAPL];
    __shared__ u32 li[CAPL];
    __shared__ u32 h[1024];
    __shared__ u32 cs[256];
    __shared__ u32 s_usb, s_R2, s_tc;
    __shared__ u32 tk[256], ti[256];
    const int g = blockIdx.x, t = threadIdx.x;
    if (meta[16 + g]) return;                 // take-all group (uniform return)
    u32 c = meta[24 + g];
    if (c > CAPL) c = CAPL;
    const u32 R1 = meta[8 + g];
    for (u32 j = t; j < c; j += 256) {        // O(c/256) iters, O(1) body
        lk[j] = list[(g * CAPL + j) * 2];
        li[j] = list[(g * CAPL + j) * 2 + 1];
    }
    for (u32 b = t; b < 1024; b += 256) h[b] = 0;
    if (t == 0) s_tc = 0;
    __syncthreads();
    for (u32 j = t; j < c; j += 256) atomicAdd(&h[(lk[j] >> 11) & 1023u], 1u);
    __syncthreads();
    // suffix scan over 1024 sub-bins (4 bins/thread + 256-chunk scan)
    u32 loc[4];
    u32 s = 0;
    #pragma unroll
    for (int j = 0; j < 4; ++j) { loc[j] = h[t * 4 + j]; s += loc[j]; }
    cs[t] = s;
    __syncthreads();
    for (int d = 1; d < 256; d <<= 1) {
        const u32 add = (t + d < 256) ? cs[t + d] : 0u;
        __syncthreads();
        cs[t] += add;
        __syncthreads();
    }
    u32 run = (t < 255) ? cs[t + 1] : 0u;
    #pragma unroll
    for (int j = 3; j >= 0; --j) {
        const u32 Sj = run + loc[j];
        if (Sj >= R1 && run < R1) { s_usb = (u32)(t * 4 + j); s_R2 = R1 - run; }
        run = Sj;
    }
    __syncthreads();
    const u32 usb = s_usb, R2 = s_R2;
    const int n = g >> 1;
    const bool posg = ((g & 1) == 0);
    const size_t NK = (size_t)NI * KA;
    // classify members: sub-bin above boundary -> in; equal -> tiny tie set
    for (u32 j = t; j < c; j += 256) {
        const u32 sb = (lk[j] >> 11) & 1023u;
        if (sb > usb) {
            const int o = n * KA + (int)li[j];
            out[5 * NK + o] = 1.0f;
            if (posg) out[6 * NK + o] = 1.0f;
        } else if (sb == usb) {
            const u32 p = atomicAdd(&s_tc, 1u);
            if (p < 256) { tk[p] = lk[j]; ti[p] = li[j]; }
        }
    }
    __syncthreads();
    u32 tc = s_tc;
    if (tc > 256) tc = 256;
    // rank the tie set (typically 1-3 members) by (key desc, idx asc)
    for (u32 i = t; i < tc; i += 256) {
        const u32 ki = tk[i], ii = ti[i];
        u32 rank = 0;
        for (u32 j = 0; j < tc; ++j) {
            const u32 kj = tk[j];
            if (kj > ki || (kj == ki && ti[j] < ii)) rank++;
        }
        if (rank < R2) {
            const int o = n * KA + (int)ii;
            out[5 * NK + o] = 1.0f;
            if (posg) out[6 * NK + o] = 1.0f;
        }
    }
}

extern "C" void kernel_launch(void* const* d_in, const int* in_sizes, int n_in,
                              void* d_out, int out_size, void* d_ws, size_t ws_size,
                              hipStream_t stream) {
    (void)in_sizes; (void)n_in; (void)out_size; (void)ws_size;
    const void* anchors = d_in[0];   // (K,4)  f32 (bf16 fallback sniffed)
    const void* scores  = d_in[1];   // (N,K)
    const void* gtb     = d_in[2];   // (N,M,4)
    const int*  glab    = (const int*)d_in[3];   // (N,M) int32
    float* out = (float*)d_out;

    u32* ws   = (u32*)d_ws;
    u32* hist = ws;
    u32* meta = ws + METAO;
    u32* list = ws + LISTO;
    u32* keys = ws + KEYSO;
    u8*  flags = (u8*)((char*)d_ws + FLAGO_BYTES);

    const int GB4 = (KA / 4 + 255) / 256;   // 235
    kInit<<<64, 256, 0, stream>>>((const float*)anchors, ws);
    AnchorTargetLayer_48052094107725_kernel<<<dim3(GB4, NI), 256, 0, stream>>>(
        anchors, scores, gtb, glab, out, keys, flags, hist, ws);
    kB<<<8, 256, 0, stream>>>(hist, meta);
    kFT<<<(NI * KA / 4 + 255) / 256, 256, 0, stream>>>(keys, (const u32*)flags, meta, list, out);
    kR2<<<8, 256, 0, stream>>>(meta, list, out);
}

// Round 15
// 137.533 us; speedup vs baseline: 2.3673x; 1.0146x over previous
//
#include <hip/hip_runtime.h>

// Problem constants (from reference)
#define KA 240000
#define NI 4
#define MG 50
#define NSEL 256u
#define CAPL 4096          // boundary-bin member cap per group (expect ~260)
#define BPI 235            // blocks per image: 235*256*4 = 240640 >= 240000
#define GRID (BPI * NI)    // 940 blocks

typedef unsigned int u32;

// ws layout (u32 units): hist 8x2048 @0 | meta[32] @16384 | list @16416 (8*CAPL*2)
// meta: us[0..8) | R[8..16) | done[16..24) | cnt[24..32)
#define METAO 16384
#define LISTO (METAO + 32)

// monotone f32 -> u32 sortkey (order-preserving for all finite floats)
static __device__ __forceinline__ u32 sortkey32(float f) {
    u32 b = __float_as_uint(f);
    return (b & 0x80000000u) ? ~b : (b | 0x80000000u);
}

// ---------------- D1: fused zero + exact-f32 IoU/argmax + targets + histogram ----------------
// Inputs are f32 (established R5-R13). Zeroing is fused: each block atomically zeroes
// an 18-word slice of hist/meta at block START; merge atomics happen at block END
// (~40us later). Grid 940 <= co-resident capacity at __launch_bounds__(256,4), so all
// blocks start together (guide-sanctioned capacity argument). atomicExch (not plain
// store) keeps the zeroes coherent with the cross-XCD atomicAdd merges.
extern "C" __global__ void __launch_bounds__(256, 4)
AnchorTargetLayer_48052094107725_kernel(
    const float4* __restrict__ anchors, const float* __restrict__ scores,
    const float4* __restrict__ gtb, const int* __restrict__ glab,
    float* __restrict__ out, u32* __restrict__ flags, u32* __restrict__ ws) {
#pragma clang fp contract(off)
    __shared__ float4 gA[MG];
    __shared__ int glb[MG];
    __shared__ u32 lh[2048];        // packed hist: pos count low16 | neg count high16
    const int bx = blockIdx.x;
    const int tid = threadIdx.x;
    const int n = bx / BPI;
    const int kb = bx - n * BPI;

    if (tid < 18) {
        const int i = bx * 18 + tid;      // 940*18 = 16920 >= 16416
        if (i < LISTO) atomicExch(&ws[i], 0u);
    }
    for (int i = tid; i < 2048; i += 256) lh[i] = 0;
    if (tid < MG) {
        gA[tid] = gtb[n * MG + tid];
        glb[tid] = glab[n * MG + tid];
    }
    __syncthreads();

    const int k0 = (kb * 256 + tid) * 4;   // 4 consecutive anchors (KA%4==0)
    if (k0 < KA) {
        float ax0[4], ay0[4], ax2[4], ay2[4];
        #pragma unroll
        for (int j = 0; j < 4; ++j) {
            const float4 A = anchors[k0 + j];
            ax0[j] = A.x; ay0[j] = A.y; ax2[j] = A.z; ay2[j] = A.w;
        }
        float aaw[4], aah[4], aar[4], bst[4];
        int bix[4];
        #pragma unroll
        for (int j = 0; j < 4; ++j) {
            aaw[j] = ax2[j] - ax0[j];
            aah[j] = ay2[j] - ay0[j];
            aar[j] = aaw[j] * aah[j];
            bst[j] = -1.0f;
            bix[j] = 0;
        }
        for (int m = 0; m < MG; m += 2) {
            const float4 Ga = gA[m];
            const float4 Gb = gA[m + 1];
            const float gaA = (Ga.z - Ga.x) * (Ga.w - Ga.y);   // same ops as reference
            const float gaB = (Gb.z - Gb.x) * (Gb.w - Gb.y);
            #pragma unroll
            for (int j = 0; j < 4; ++j) {
                const float wa = fmaxf(fminf(ax2[j], Ga.z) - fmaxf(ax0[j], Ga.x), 0.0f);
                const float ha = fmaxf(fminf(ay2[j], Ga.w) - fmaxf(ay0[j], Ga.y), 0.0f);
                const float ia = wa * ha;
                const float qa = ia / (((aar[j] + gaA) - ia) + 1e-8f);  // IEEE f32 div
                const float wb = fmaxf(fminf(ax2[j], Gb.z) - fmaxf(ax0[j], Gb.x), 0.0f);
                const float hb = fmaxf(fminf(ay2[j], Gb.w) - fmaxf(ay0[j], Gb.y), 0.0f);
                const float ib = wb * hb;
                const float qb = ib / (((aar[j] + gaB) - ib) + 1e-8f);
                if (qa > bst[j]) { bst[j] = qa; bix[j] = m; }       // strict >: first idx
                if (qb > bst[j]) { bst[j] = qb; bix[j] = m + 1; }
            }
        }

        const int nk = n * KA + k0;
        const float4 s4 = ((const float4*)scores)[nk >> 2];
        const float scv[4] = {s4.x, s4.y, s4.z, s4.w};

        float clsv[4];
        float4 regv[4];
        u32 flagpack = 0;
        #pragma unroll
        for (int j = 0; j < 4; ++j) {
            const bool pos = bst[j] >= 0.7f;
            const bool neg = bst[j] < 0.3f;
            clsv[j] = pos ? (float)glb[bix[j]] : 0.0f;
            float4 rv = make_float4(0.0f, 0.0f, 0.0f, 0.0f);
            if (pos) {
                const float4 Gm = gA[bix[j]];
                const float gw = Gm.z - Gm.x, gh = Gm.w - Gm.y;
                const float gcx = Gm.x + 0.5f * gw, gcy = Gm.y + 0.5f * gh;
                const float acx = ax0[j] + 0.5f * aaw[j], acy = ay0[j] + 0.5f * aah[j];
                rv.x = (gcx - acx) / aaw[j];
                rv.y = (gcy - acy) / aah[j];
                rv.z = logf(gw / aaw[j]);
                rv.w = logf(gh / aah[j]);
            }
            regv[j] = rv;
            const u32 fl = pos ? 1u : (neg ? 2u : 0u);
            flagpack |= fl << (8 * j);
            if (fl) atomicAdd(&lh[sortkey32(scv[j]) >> 21], fl == 2u ? 0x10000u : 1u);
        }
        const size_t NK = (size_t)NI * KA;
        ((float4*)out)[nk >> 2] = make_float4(clsv[0], clsv[1], clsv[2], clsv[3]);
        float4* regp = ((float4*)(out + NK)) + nk;
        regp[0] = regv[0]; regp[1] = regv[1]; regp[2] = regv[2]; regp[3] = regv[3];
        flags[nk >> 2] = flagpack;
    }
    __syncthreads();
    // merge packed LDS histogram into per-group global hist
    const int gp = 2 * n;
    for (int i = tid; i < 2048; i += 256) {
        const u32 c = lh[i];
        if (c & 0xFFFFu) atomicAdd(&ws[gp * 2048 + i], c & 0xFFFFu);
        if (c >> 16)     atomicAdd(&ws[(gp + 1) * 2048 + i], c >> 16);
    }
}

// ---------------- D2: per-block boundary scan + weights + tie collection ----------------
__global__ void __launch_bounds__(256) kW(const float* __restrict__ scores,
                                          const u32* __restrict__ flagsW,
                                          u32* __restrict__ ws,
                                          float* __restrict__ out) {
    __shared__ u32 cs[256];
    __shared__ u32 s_us[2], s_R[2], s_done[2];
    const int bx = blockIdx.x, tid = threadIdx.x;
    const int n = bx / BPI, kb = bx - n * BPI;
    u32* hist = ws;
    u32* meta = ws + METAO;
    u32* list = ws + LISTO;

    // boundary for both groups of this image (redundant per block; hist is L2-hot)
    for (int gi = 0; gi < 2; ++gi) {
        const int g = 2 * n + gi;
        u32 loc[8];
        u32 s = 0;
        const int base = g * 2048 + tid * 8;
        #pragma unroll
        for (int j = 0; j < 8; ++j) { loc[j] = hist[base + j]; s += loc[j]; }
        cs[tid] = s;
        __syncthreads();
        for (int d = 1; d < 256; d <<= 1) {
            const u32 add = (tid + d < 256) ? cs[tid + d] : 0u;
            __syncthreads();
            cs[tid] += add;
            __syncthreads();
        }
        if (tid == 0) s_done[gi] = (cs[0] < NSEL) ? 1u : 0u;
        u32 run = (tid < 255) ? cs[tid + 1] : 0u;
        #pragma unroll
        for (int j = 7; j >= 0; --j) {
            const u32 Sj = run + loc[j];
            if (Sj >= NSEL && run < NSEL) {
                s_us[gi] = (u32)(tid * 8 + j);   // boundary 11-bit prefix
                s_R[gi] = NSEL - run;            // slots within boundary bin
            }
            run = Sj;
        }
        __syncthreads();
    }
    if (kb == 0 && tid == 0) {                   // publish for D3 (one writer/image)
        meta[2 * n] = s_us[0];     meta[8 + 2 * n] = s_R[0];     meta[16 + 2 * n] = s_done[0];
        meta[2 * n + 1] = s_us[1]; meta[8 + 2 * n + 1] = s_R[1]; meta[16 + 2 * n + 1] = s_done[1];
    }

    const int k0 = (kb * 256 + tid) * 4;
    if (k0 >= KA) return;
    const int nk = n * KA + k0;
    const float4 s4 = ((const float4*)scores)[nk >> 2];
    const float scv[4] = {s4.x, s4.y, s4.z, s4.w};
    const u32 fw = flagsW[nk >> 2];
    float cw[4], rw[4];
    #pragma unroll
    for (int j = 0; j < 4; ++j) {
        const u32 f = (fw >> (8 * j)) & 255u;
        bool in = false;
        if (f) {
            const int gi = (f == 2u) ? 1 : 0;
            if (s_done[gi]) {
                in = true;                        // group < 256 members: take all
            } else {
                const u32 key = sortkey32(scv[j]);
                const u32 p11 = key >> 21;
                if (p11 > s_us[gi]) {
                    in = true;
                } else if (p11 == s_us[gi]) {
                    // boundary-bin member: defer verdict to D3 (weight stays 0)
                    const int g = 2 * n + gi;
                    const u32 p = atomicAdd(&meta[24 + g], 1u);
                    if (p < CAPL) {
                        list[(g * CAPL + p) * 2] = key;
                        list[(g * CAPL + p) * 2 + 1] = (u32)(k0 + j);
                    }
                }
            }
        }
        cw[j] = in ? 1.0f : 0.0f;
        rw[j] = (in && f == 1u) ? 1.0f : 0.0f;
    }
    const size_t NK4 = (size_t)(NI * KA) / 4;
    ((float4*)out)[5 * NK4 + (nk >> 2)] = make_float4(cw[0], cw[1], cw[2], cw[3]);
    ((float4*)out)[6 * NK4 + (nk >> 2)] = make_float4(rw[0], rw[1], rw[2], rw[3]);
}

// ---------------- D3: boundary-bin refinement + fixups (8 blocks) ----------------
__global__ void __launch_bounds__(256) kR2(const u32* __restrict__ ws,
                                           float* __restrict__ out) {
    __shared__ u32 h2[1024];
    __shared__ u32 cs[256];
    __shared__ u32 s_usb, s_R2, s_tc;
    __shared__ u32 tk[256], ti[256];
    const u32* meta = ws + METAO;
    const u32* list = ws + LISTO;
    const int g = blockIdx.x, tid = threadIdx.x;
    if (meta[16 + g]) return;                 // take-all group (uniform return)
    u32 c = meta[24 + g];
    if (c > CAPL) c = CAPL;
    const u32 R1 = meta[8 + g];
    for (u32 i = tid; i < 1024; i += 256) h2[i] = 0;
    if (tid == 0) s_tc = 0;
    __syncthreads();
    for (u32 j = tid; j < c; j += 256)
        atomicAdd(&h2[(list[(g * CAPL + j) * 2] >> 11) & 1023u], 1u);
    __syncthreads();
    // suffix scan over 1024 sub-bins
    u32 loc[4];
    u32 s = 0;
    #pragma unroll
    for (int j = 0; j < 4; ++j) { loc[j] = h2[tid * 4 + j]; s += loc[j]; }
    cs[tid] = s;
    __syncthreads();
    for (int d = 1; d < 256; d <<= 1) {
        const u32 add = (tid + d < 256) ? cs[tid + d] : 0u;
        __syncthreads();
        cs[tid] += add;
        __syncthreads();
    }
    u32 run = (tid < 255) ? cs[tid + 1] : 0u;
    #pragma unroll
    for (int j = 3; j >= 0; --j) {
        const u32 Sj = run + loc[j];
        if (Sj >= R1 && run < R1) { s_usb = (u32)(tid * 4 + j); s_R2 = R1 - run; }
        run = Sj;
    }
    __syncthreads();
    const u32 usb = s_usb, R2 = s_R2;
    const int nn = g >> 1;
    const bool posg = ((g & 1) == 0);
    const size_t NK = (size_t)NI * KA;
    for (u32 j = tid; j < c; j += 256) {
        const u32 key = list[(g * CAPL + j) * 2];
        const u32 idx = list[(g * CAPL + j) * 2 + 1];
        const u32 sb = (key >> 11) & 1023u;
        if (sb > usb) {
            const int o = nn * KA + (int)idx;
            out[5 * NK + o] = 1.0f;
            if (posg) out[6 * NK + o] = 1.0f;
        } else if (sb == usb) {
            const u32 p = atomicAdd(&s_tc, 1u);
            if (p < 256) { tk[p] = key; ti[p] = idx; }
        }
    }
    __syncthreads();
    u32 tc = s_tc;
    if (tc > 256) tc = 256;
    // rank tiny tie set by (key desc, idx asc) — stable top_k semantics
    for (u32 i = tid; i < tc; i += 256) {
        const u32 ki = tk[i], ii = ti[i];
        u32 rank = 0;
        for (u32 j = 0; j < tc; ++j) {
            const u32 kj = tk[j];
            if (kj > ki || (kj == ki && ti[j] < ii)) rank++;
        }
        if (rank < R2) {
            const int o = nn * KA + (int)ii;
            out[5 * NK + o] = 1.0f;
            if (posg) out[6 * NK + o] = 1.0f;
        }
    }
}

extern "C" void kernel_launch(void* const* d_in, const int* in_sizes, int n_in,
                              void* d_out, int out_size, void* d_ws, size_t ws_size,
                              hipStream_t stream) {
    (void)in_sizes; (void)n_in; (void)out_size; (void)ws_size;
    const float4* anchors = (const float4*)d_in[0];   // (K,4) f32
    const float*  scores  = (const float*)d_in[1];    // (N,K) f32
    const float4* gtb     = (const float4*)d_in[2];   // (N,M,4) f32
    const int*    glab    = (const int*)d_in[3];      // (N,M) int32
    float* out = (float*)d_out;

    u32* ws = (u32*)d_ws;
    u32* flags = ws + LISTO + 8 * CAPL * 2;           // u32 per 4 anchors

    AnchorTargetLayer_48052094107725_kernel<<<GRID, 256, 0, stream>>>(
        anchors, scores, gtb, glab, out, flags, ws);
    kW<<<GRID, 256, 0, stream>>>(scores, flags, ws, out);
    kR2<<<8, 256, 0, stream>>>(ws, out);
}